// Round 1
// baseline (44.253 us; speedup 1.0000x reference)
//
#include <hip/hip_runtime.h>

#define LOG2E 1.4426950408889634f

// Derived params per tuple (Cout,Cin,NB,KH,KW) flat:
//   {Ec, 0.2*Ec, 2*LOG2E*k, 2*Ps*coef}
__global__ void derive_kernel(const float* __restrict__ kk,
                              const float* __restrict__ Ec,
                              const float* __restrict__ Ps,
                              const float* __restrict__ coef,
                              float4* __restrict__ dp, int n) {
    int i = blockIdx.x * blockDim.x + threadIdx.x;
    if (i < n) {
        float e = Ec[i];
        dp[i] = make_float4(e, 0.2f * e, 2.0f * LOG2E * kk[i], 2.0f * Ps[i] * coef[i]);
    }
}

// K0[co] = out_bias[co] + sum over 432 tuples of coef*(Ps+bias)
__global__ void k0_kernel(const float* __restrict__ Ps,
                          const float* __restrict__ bias,
                          const float* __restrict__ coef,
                          const float* __restrict__ out_bias,
                          float* __restrict__ K0) {
    int co = blockIdx.x;
    int tid = threadIdx.x;   // 64 threads = 1 wave
    float sum = 0.f;
    for (int j = tid; j < 432; j += 64) {
        int idx = co * 432 + j;
        sum += coef[idx] * (Ps[idx] + bias[idx]);
    }
    #pragma unroll
    for (int off = 32; off >= 1; off >>= 1) sum += __shfl_down(sum, off, 64);
    if (tid == 0) K0[co] = sum + out_bias[co];
}

// Output (B=4, Cout=32, H=32, W=32). Block = 256 threads = 8 rows x 32 cols.
// bid = ((b*32 + co)*4 + hchunk)  -> co is blockIdx-derived => wave-uniform
// => all param loads become scalar s_load_dwordx4.
__global__ __launch_bounds__(256) void main_kernel(
    const float* __restrict__ x, const float4* __restrict__ dp,
    const float* __restrict__ K0, float* __restrict__ out) {
    const int bid = blockIdx.x;
    const int tid = threadIdx.x;
    const int hc = bid & 3;
    const int co = (bid >> 2) & 31;
    const int b  = bid >> 7;
    const int w = tid & 31;
    const int h = hc * 8 + (tid >> 5);

    const float C1 = 10.0f * LOG2E;  // cn = rcp(1 + exp2(C1*s)), s = x+Ec

    float acc = 0.f;
    const float4* dpc = dp + co * 432;          // + ci*27 + nb*9 + kh*3 + kw
    const float* xb = x + b * 16 * 1024;

    for (int ci = 0; ci < 16; ++ci) {
        const float* xc = xb + ci * 1024;
        const float4* dpi = dpc + ci * 27;
        #pragma unroll
        for (int kh = 0; kh < 3; ++kh) {
            int hy = h + kh - 1;
            bool rowok = (unsigned)hy < 32u;
            #pragma unroll
            for (int kw = 0; kw < 3; ++kw) {
                int wx = w + kw - 1;
                bool ok = rowok && ((unsigned)wx < 32u);
                float xv = ok ? xc[hy * 32 + wx] : 0.f;
                #pragma unroll
                for (int nb = 0; nb < 3; ++nb) {
                    float4 P = dpi[nb * 9 + kh * 3 + kw];
                    float s  = xv + P.x;
                    float e1 = __builtin_amdgcn_exp2f(C1 * s);
                    float cn = __builtin_amdgcn_rcpf(1.0f + e1);
                    float sh = __builtin_fmaf(-P.y, cn, s);       // s - 0.2Ec*cn
                    float e2 = __builtin_amdgcn_exp2f(P.z * sh);
                    float r2 = __builtin_amdgcn_rcpf(1.0f + e2);
                    acc = __builtin_fmaf(-P.w, r2, acc);          // -= 2*Ps*coef * r2
                }
            }
        }
    }
    int o = ((b * 32 + co) * 32 + h) * 32 + w;
    out[o] = acc + K0[co];
}

extern "C" void kernel_launch(void* const* d_in, const int* in_sizes, int n_in,
                              void* d_out, int out_size, void* d_ws, size_t ws_size,
                              hipStream_t stream) {
    const float* x        = (const float*)d_in[0];
    const float* k        = (const float*)d_in[1];
    const float* Ec       = (const float*)d_in[2];
    const float* Ps       = (const float*)d_in[3];
    const float* bias     = (const float*)d_in[4];
    const float* coef     = (const float*)d_in[5];
    const float* out_bias = (const float*)d_in[6];
    float* out = (float*)d_out;

    const int NP = 32 * 16 * 3 * 3 * 3;  // 13824
    float4* dp = (float4*)d_ws;
    float* K0  = (float*)((char*)d_ws + (size_t)NP * sizeof(float4));

    derive_kernel<<<(NP + 255) / 256, 256, 0, stream>>>(k, Ec, Ps, coef, dp, NP);
    k0_kernel<<<32, 64, 0, stream>>>(Ps, bias, coef, out_bias, K0);
    main_kernel<<<512, 256, 0, stream>>>(x, dp, K0, out);
}